// Round 10
// baseline (345.371 us; speedup 1.0000x reference)
//
#include <hip/hip_runtime.h>
#include <hip/hip_bf16.h>

// Problem constants
#define BATCH   65536
#define HW      28
#define OHW     26
#define HID     200
#define NCLS    10
#define MT2     32                  // images per gemm block (2 m-tiles)
#define GBLOCKS (BATCH / MT2)       // 2048
#define KC1     25                  // K-chunks: 784 padded to 800 = 25*32
#define RSH     832                 // LDS shorts per image row (1664 B; 416 dw ≡ 0 mod 32)

typedef __attribute__((ext_vector_type(8))) __bf16 bf16x8;
typedef __attribute__((ext_vector_type(4))) float  f32x4;

__device__ __forceinline__ unsigned int pk2(float a, float b) {
  __hip_bfloat16 ha = __float2bfloat16(a), hb = __float2bfloat16(b);
  return (unsigned int)__builtin_bit_cast(unsigned short, ha)
       | ((unsigned int)__builtin_bit_cast(unsigned short, hb) << 16);
}

// fslot: A-fragment layout with XOR swizzle, used ONLY for hidA overlay.
__device__ __forceinline__ unsigned short* fslot(unsigned short* base, int m, int k) {
  const int kc = k >> 5;
  return base + ((kc * 64 + ((k >> 3) & 3) * 16 + (m ^ (kc & 7))) * 8) + (k & 7);
}

// ---------------------------------------------------------------------------
// prep_w1e: fold the 3x3 conv into w1 (feat = x*C^T => x @ (C^T w1)).
// B-fragment order: chunk c = (kc*13+nt)*64 + lane holds j=0..7 of
// k=kc*32+(lane>>4)*8+j, n = nt*16+(lane&15)  (K pad 800, N pad 208).
// ---------------------------------------------------------------------------
__global__ __launch_bounds__(256) void prep_w1e(const float* __restrict__ w1,
                                                const float* __restrict__ cwp,
                                                unsigned short* __restrict__ w1e) {
  int c = blockIdx.x * 256 + threadIdx.x;
  if (c >= KC1 * 13 * 64) return;
  int lane = c & 63, g = c >> 6;
  int kc = g / 13, nt = g - kc * 13;
  int ln = lane & 15, qd = lane >> 4;
  int n = nt * 16 + ln;
  float cw[9];
  #pragma unroll
  for (int t = 0; t < 9; ++t) cw[t] = cwp[t];
  float v[8];
  #pragma unroll
  for (int j = 0; j < 8; ++j) {
    int k = kc * 32 + qd * 8 + j;
    float s = 0.f;
    if (k < 784 && n < HID) {
      int ri = k / 28, ci = k - ri * 28;
      #pragma unroll
      for (int di = 0; di < 3; ++di) {
        int r = ri - di;
        if (r >= 0 && r < OHW) {
          #pragma unroll
          for (int dj = 0; dj < 3; ++dj) {
            int cc = ci - dj;
            if (cc >= 0 && cc < OHW) s += cw[di * 3 + dj] * w1[(r * OHW + cc) * HID + n];
          }
        }
      }
    }
    v[j] = s;
  }
  uint4 o = make_uint4(pk2(v[0], v[1]), pk2(v[2], v[3]),
                       pk2(v[4], v[5]), pk2(v[6], v[7]));
  *(uint4*)(w1e + (size_t)c * 8) = o;
}

// w2 (200x10 f32) -> bf16 B-fragment order, K=224 N=16 padded. 7 KB.
__global__ __launch_bounds__(256) void prep_w2f(const float* __restrict__ w2,
                                                unsigned short* __restrict__ w2f) {
  int c = blockIdx.x * 256 + threadIdx.x;
  if (c >= 7 * 64) return;
  int lane = c & 63, kc = c >> 6;
  int col = lane & 15;
  float v[8];
  #pragma unroll
  for (int j = 0; j < 8; ++j) {
    int k = kc * 32 + (lane >> 4) * 8 + j;
    v[j] = (col < NCLS && k < HID) ? w2[k * NCLS + col] : 0.f;
  }
  uint4 o = make_uint4(pk2(v[0], v[1]), pk2(v[2], v[3]),
                       pk2(v[4], v[5]), pk2(v[6], v[7]));
  *(uint4*)(w2f + (size_t)c * 8) = o;
}

// ---------------------------------------------------------------------------
// GEMM1 compute: barrier-free K-loop. A from read-only swizzled LDS
// (8-clock-floor b128 reads), B via depth-1 register prefetch from L2-hot
// w1e. acc stays in registers; epilogue runs after an external barrier.
// ---------------------------------------------------------------------------
template<int NT0, int NT>
__device__ __forceinline__ void gemm1_compute(
    const unsigned short* __restrict__ w1e, const unsigned short* sh,
    int lane, f32x4 (&acc)[2][4]) {
  const int ln = lane & 15, qd = lane >> 4;
  bf16x8 bCur[NT];
  #pragma unroll
  for (int t = 0; t < NT; ++t)
    bCur[t] = *(const bf16x8*)(w1e + ((size_t)((NT0 + t) * 64 + lane)) * 8);
  const int sw = (ln & 7) << 3;
  for (int kc = 0; kc < KC1; ++kc) {
    bf16x8 bNx[NT];
    if (kc + 1 < KC1) {
      #pragma unroll
      for (int t = 0; t < NT; ++t)
        bNx[t] = *(const bf16x8*)(w1e +
                   ((size_t)((kc + 1) * 13 + NT0 + t) * 64 + lane) * 8);
    }
    bf16x8 a[2];
    #pragma unroll
    for (int mi = 0; mi < 2; ++mi)
      a[mi] = *(const bf16x8*)&sh[(((mi * 16 + ln) * RSH) + kc * 32 + qd * 8) ^ sw];
    #pragma unroll
    for (int t = 0; t < NT; ++t)
      #pragma unroll
      for (int mi = 0; mi < 2; ++mi)
        acc[mi][t] = __builtin_amdgcn_mfma_f32_16x16x32_bf16(a[mi], bCur[t],
                                                             acc[mi][t], 0, 0, 0);
    if (kc + 1 < KC1) {
      #pragma unroll
      for (int t = 0; t < NT; ++t) bCur[t] = bNx[t];
    }
  }
}

template<int NT0, int NT>
__device__ __forceinline__ void gemm1_epilogue(
    const float* __restrict__ b1, unsigned short* hidA, int lane,
    f32x4 (&acc)[2][4]) {
  const int ln = lane & 15, qd = lane >> 4;
  #pragma unroll
  for (int t = 0; t < NT; ++t) {
    const int n = (NT0 + t) * 16 + ln;
    if (n < HID) {
      const float bias = b1[n];
      const int kc2 = n >> 5, qd2 = (n >> 3) & 3, j2 = n & 7, c2 = kc2 & 7;
      #pragma unroll
      for (int mi = 0; mi < 2; ++mi)
        #pragma unroll
        for (int rr = 0; rr < 4; ++rr) {
          const int m = qd * 4 + rr;
          float h = fmaxf(acc[mi][t][rr] + bias, 0.f);
          __hip_bfloat16 hb = __float2bfloat16(h);
          hidA[mi * 3584 + (kc2 * 64 + qd2 * 16 + (m ^ c2)) * 8 + j2] =
              __builtin_bit_cast(unsigned short, hb);
        }
    }
  }
}

// ---------------------------------------------------------------------------
// fused9: x read as ONE contiguous 100 KB stream per block (wave-wide 1 KB
// dwordx4 bursts, sequential across blocks) -> DRAM sees large sequential
// bursts instead of scattered 128 B strips. Stage -> swizzled LDS; K-loop
// barrier-free; hidA overlays sh after a full barrier.
// Swizzle: short idx (row*832 + e) ^ ((row&7)<<3). Row stride 416 dw ≡ 0
// mod 32 banks; XOR spreads the 16 fragment rows -> b128 reads at the
// 8-clock floor, stage writes conflict-free (row-uniform contiguous).
// ---------------------------------------------------------------------------
__global__ __launch_bounds__(256, 3) void fused9(
    const float* __restrict__ x, const unsigned short* __restrict__ w1e,
    const unsigned short* __restrict__ w2f, const float* __restrict__ b1,
    const float* __restrict__ b2, float* __restrict__ out) {
  __shared__ __align__(16) unsigned short sh[MT2 * RSH];   // 53,248 B -> 3 blk/CU
  const int tid  = threadIdx.x;
  const int wave = tid >> 6;
  const int lane = tid & 63;
  const int blk32 = blockIdx.x * MT2;

  // ---- stage: wave w -> image rows 8w..8w+7 (contiguous 100 KB block slab).
  // Per row: 3 wave-wide iterations x 256 floats (64 lanes x float4 = 1 KB
  // burst) cover elems 0..767; tail 768..783 by lanes 0-3; pad 784..831 = 0.
  #pragma unroll
  for (int r8 = 0; r8 < 8; ++r8) {
    const int row = wave * 8 + r8;
    const float* xr = x + (size_t)(blk32 + row) * 784;
    const int base = row * RSH;
    const int swz = (row & 7) << 3;
    #pragma unroll
    for (int i = 0; i < 3; ++i) {
      const int e = i * 256 + lane * 4;
      const float4 f = *(const float4*)(xr + e);
      *(uint2*)&sh[(base + e) ^ swz] = make_uint2(pk2(f.x, f.y), pk2(f.z, f.w));
    }
    if (lane < 4) {
      const int e = 768 + lane * 4;
      const float4 f = *(const float4*)(xr + e);
      *(uint2*)&sh[(base + e) ^ swz] = make_uint2(pk2(f.x, f.y), pk2(f.z, f.w));
    } else if (lane < 16) {
      const int e = 768 + lane * 4;                      // elems 784..831 -> 0
      *(uint2*)&sh[(base + e) ^ swz] = make_uint2(0u, 0u);
    }
  }
  __syncthreads();   // stage complete (one-time full drain is fine)

  // ---- GEMM1 compute (barrier-free), acc held in registers ----
  f32x4 acc[2][4];
  #pragma unroll
  for (int mi = 0; mi < 2; ++mi)
    #pragma unroll
    for (int t = 0; t < 4; ++t) acc[mi][t] = (f32x4){0.f, 0.f, 0.f, 0.f};
  switch (wave) {
    case 0:  gemm1_compute<0, 4>(w1e, sh, lane, acc); break;
    case 1:  gemm1_compute<4, 3>(w1e, sh, lane, acc); break;
    case 2:  gemm1_compute<7, 3>(w1e, sh, lane, acc); break;
    default: gemm1_compute<10, 3>(w1e, sh, lane, acc); break;
  }
  __syncthreads();   // ALL waves' A-reads done -> overlay hidA on sh

  // zero hid K-pad (k=200..223): 2 tiles x 16 rows x 12 dwords
  for (int i = tid; i < 384; i += 256) {
    int mi = i / 192, r = i - mi * 192, m = r / 12, d = r - m * 12;
    *(unsigned int*)fslot(sh + mi * 3584, m, 200 + 2 * d) = 0u;
  }
  switch (wave) {
    case 0:  gemm1_epilogue<0, 4>(b1, sh, lane, acc); break;
    case 1:  gemm1_epilogue<4, 3>(b1, sh, lane, acc); break;
    case 2:  gemm1_epilogue<7, 3>(b1, sh, lane, acc); break;
    default: gemm1_epilogue<10, 3>(b1, sh, lane, acc); break;
  }
  __syncthreads();   // hidA complete (incl. pads)

  // ---- GEMM2: waves 0,1 handle m-tiles 0,1. 7 MFMA over K=224 ----
  if (wave < 2) {
    const int ln = lane & 15, qd = lane >> 4;
    f32x4 acc2 = (f32x4){0.f, 0.f, 0.f, 0.f};
    #pragma unroll
    for (int kc = 0; kc < 7; ++kc) {
      bf16x8 a = *(const bf16x8*)&sh[wave * 3584 + (kc * 64 + (lane ^ (kc & 7))) * 8];
      bf16x8 b = *(const bf16x8*)(w2f + ((size_t)kc * 64 + lane) * 8);
      acc2 = __builtin_amdgcn_mfma_f32_16x16x32_bf16(a, b, acc2, 0, 0, 0);
    }
    if (ln < NCLS) {
      const float bb = b2[ln];
      #pragma unroll
      for (int rr = 0; rr < 4; ++rr) {
        out[((size_t)(blockIdx.x * 2 + wave) * 16 + qd * 4 + rr) * NCLS + ln] =
            acc2[rr] + bb;
      }
    }
  }
}

extern "C" void kernel_launch(void* const* d_in, const int* in_sizes, int n_in,
                              void* d_out, int out_size, void* d_ws, size_t ws_size,
                              hipStream_t stream) {
  const float* x  = (const float*)d_in[0];
  const float* cw = (const float*)d_in[1];
  const float* w1 = (const float*)d_in[2];
  const float* b1 = (const float*)d_in[3];
  const float* w2 = (const float*)d_in[4];
  const float* b2 = (const float*)d_in[5];
  float* out = (float*)d_out;

  unsigned short* w1e = (unsigned short*)d_ws;                      // 332,800 B
  unsigned short* w2f = (unsigned short*)((char*)d_ws + 335872);    //   7,168 B

  hipLaunchKernelGGL(prep_w1e, dim3((KC1 * 13 * 64 + 255) / 256), dim3(256), 0, stream,
                     w1, cw, w1e);
  hipLaunchKernelGGL(prep_w2f, dim3(2), dim3(256), 0, stream, w2, w2f);
  hipLaunchKernelGGL(fused9, dim3(GBLOCKS), dim3(256), 0, stream,
                     x, w1e, w2f, b1, b2, out);
}

// Round 11
// 325.622 us; speedup vs baseline: 1.0607x; 1.0607x over previous
//
#include <hip/hip_runtime.h>
#include <hip/hip_bf16.h>

// Problem constants
#define BATCH   65536
#define HW      28
#define OHW     26
#define HID     200
#define NCLS    10
#define MT2     64                  // images per gemm block (4 m-tiles)
#define GBLOCKS (BATCH / MT2)       // 1024
#define KC32    26                  // 32-wide B k-chunks: 784 -> 832 = 26*32
#define NSTEP   13                  // K-loop steps of BK=64

typedef __attribute__((ext_vector_type(8))) __bf16 bf16x8;
typedef __attribute__((ext_vector_type(4))) float  f32x4;

// Raw workgroup barrier WITHOUT __syncthreads()'s vmcnt(0) drain:
// lgkmcnt(0) completes this round's ds reads+writes; global prefetch loads
// stay in flight across the barrier (T3/T4: never vmcnt(0) in-loop).
#define KBAR() asm volatile("s_waitcnt lgkmcnt(0)\n\ts_barrier" ::: "memory")

__device__ __forceinline__ unsigned int pk2(float a, float b) {
  __hip_bfloat16 ha = __float2bfloat16(a), hb = __float2bfloat16(b);
  return (unsigned int)__builtin_bit_cast(unsigned short, ha)
       | ((unsigned int)__builtin_bit_cast(unsigned short, hb) << 16);
}

__device__ __forceinline__ uint4 pk8(float4 f0, float4 f1) {
  return make_uint4(pk2(f0.x, f0.y), pk2(f0.z, f0.w),
                    pk2(f1.x, f1.y), pk2(f1.z, f1.w));
}

// fslot: A-fragment layout with XOR swizzle, used ONLY for the hidA overlay.
__device__ __forceinline__ unsigned short* fslot(unsigned short* base, int m, int k) {
  const int kc = k >> 5;
  return base + ((kc * 64 + ((k >> 3) & 3) * 16 + (m ^ (kc & 7))) * 8) + (k & 7);
}

// ---------------------------------------------------------------------------
// prep_weights: one dispatch for both weight transforms.
// Blocks [0,85): w1e — conv folded into w1 (feat = x*C^T => x @ (C^T w1)),
//   B-fragment order: chunk c = (kc*13+nt)*64+lane holds j=0..7 of
//   k=kc*32+(lane>>4)*8+j (K pad 832), n=nt*16+(lane&15) (N pad 208).
// Blocks [85,87): w2f — w2 in B-fragment order, K=224, N=16 pad. 7 KB.
// ---------------------------------------------------------------------------
__global__ __launch_bounds__(256) void prep_weights(
    const float* __restrict__ w1, const float* __restrict__ cwp,
    const float* __restrict__ w2, unsigned short* __restrict__ w1e,
    unsigned short* __restrict__ w2f) {
  if (blockIdx.x < 85) {
    int c = blockIdx.x * 256 + threadIdx.x;
    if (c >= KC32 * 13 * 64) return;
    int lane = c & 63, g = c >> 6;
    int kc = g / 13, nt = g - kc * 13;
    int ln = lane & 15, qd = lane >> 4;
    int n = nt * 16 + ln;
    float cw[9];
    #pragma unroll
    for (int t = 0; t < 9; ++t) cw[t] = cwp[t];
    float v[8];
    #pragma unroll
    for (int j = 0; j < 8; ++j) {
      int k = kc * 32 + qd * 8 + j;
      float s = 0.f;
      if (k < 784 && n < HID) {
        int ri = k / 28, ci = k - ri * 28;
        #pragma unroll
        for (int di = 0; di < 3; ++di) {
          int r = ri - di;
          if (r >= 0 && r < OHW) {
            #pragma unroll
            for (int dj = 0; dj < 3; ++dj) {
              int cc = ci - dj;
              if (cc >= 0 && cc < OHW)
                s += cw[di * 3 + dj] * w1[(r * OHW + cc) * HID + n];
            }
          }
        }
      }
      v[j] = s;
    }
    *(uint4*)(w1e + (size_t)c * 8) =
        make_uint4(pk2(v[0], v[1]), pk2(v[2], v[3]),
                   pk2(v[4], v[5]), pk2(v[6], v[7]));
  } else {
    int c = (blockIdx.x - 85) * 256 + threadIdx.x;
    if (c >= 7 * 64) return;
    int lane = c & 63, kc = c >> 6;
    int col = lane & 15;
    float v[8];
    #pragma unroll
    for (int j = 0; j < 8; ++j) {
      int k = kc * 32 + (lane >> 4) * 8 + j;
      v[j] = (col < NCLS && k < HID) ? w2[k * NCLS + col] : 0.f;
    }
    *(uint4*)(w2f + (size_t)c * 8) =
        make_uint4(pk2(v[0], v[1]), pk2(v[2], v[3]),
                   pk2(v[4], v[5]), pk2(v[6], v[7]));
  }
}

// ---------------------------------------------------------------------------
// GEMM1 compute: BK=64 — 13 steps instead of 25 (halves the number of
// per-step serialization points: barriers + load-consume windows).
// Per step: prefetch x(s+1) into regs; 2 sub-chunks x {4 a ds_reads, NT
// B-loads (L2-hot w1e), 4*NT MFMA}; ds_write prefetch; KBAR.
// aBuf = sh[0..8191] (2 bufs x 4096 shorts: [h][mi*64+qd*16+row]*8).
// ---------------------------------------------------------------------------
template<int NT0, int NT>
__device__ __forceinline__ void gemm1_compute(
    const float* __restrict__ x, const unsigned short* __restrict__ w1e,
    unsigned short* sh, int lane, int tid, int blk64, f32x4 (&acc)[4][4]) {
  // staging role: thread stages TWO 16B chunks per step (h=0,1).
  const int sc_qd = (tid >> 4) & 3;
  const float* xrow =
      x + ((size_t)blk64 + (tid >> 6) * 16 + (tid & 15)) * 784;
  const int koff = sc_qd * 8;
  const int soff = tid * 8;            // (mi*64+qd*16+row)*8 == tid*8

  // prologue: stage step 0, both halves
  {
    float4 f0 = *(const float4*)(xrow + koff);
    float4 f1 = *(const float4*)(xrow + koff + 4);
    float4 g0 = *(const float4*)(xrow + 32 + koff);
    float4 g1 = *(const float4*)(xrow + 32 + koff + 4);
    *(uint4*)(sh + soff)        = pk8(f0, f1);
    *(uint4*)(sh + 2048 + soff) = pk8(g0, g1);
  }
  __syncthreads();   // one-time full drain

  int cur = 0;
  #pragma unroll
  for (int s = 0; s < NSTEP; ++s) {
    // -- prefetch x(s+1) into regs (consumed by ds_write below; loads stay
    //    in flight across KBAR into the MFMA phase)
    float4 p00, p01, p10, p11;
    const bool hav = (s + 1 < NSTEP);
    if (hav) {
      const int kb = (s + 1) * 64;
      if (s + 1 == NSTEP - 1) {                 // k 768..831: tail + pad
        if (sc_qd < 2) {
          p00 = *(const float4*)(xrow + 768 + koff);
          p01 = *(const float4*)(xrow + 768 + koff + 4);
        } else {
          p00 = (float4){0.f, 0.f, 0.f, 0.f};
          p01 = (float4){0.f, 0.f, 0.f, 0.f};
        }
        p10 = (float4){0.f, 0.f, 0.f, 0.f};     // k >= 800
        p11 = (float4){0.f, 0.f, 0.f, 0.f};
      } else {
        p00 = *(const float4*)(xrow + kb + koff);
        p01 = *(const float4*)(xrow + kb + koff + 4);
        p10 = *(const float4*)(xrow + kb + 32 + koff);
        p11 = *(const float4*)(xrow + kb + 32 + koff + 4);
      }
    }

    // -- compute: 2 sub-chunks of K=32 each
    const unsigned short* ab = sh + cur * 4096;
    #pragma unroll
    for (int h = 0; h < 2; ++h) {
      bf16x8 a[4];
      #pragma unroll
      for (int mi = 0; mi < 4; ++mi)
        a[mi] = *(const bf16x8*)(ab + h * 2048 + mi * 512 + lane * 8);
      const int kc32 = s * 2 + h;
      #pragma unroll
      for (int t = 0; t < NT; ++t) {
        bf16x8 b = *(const bf16x8*)(w1e +
                     ((size_t)(kc32 * 13 + NT0 + t) * 64 + lane) * 8);
        #pragma unroll
        for (int mi = 0; mi < 4; ++mi)
          acc[mi][t] = __builtin_amdgcn_mfma_f32_16x16x32_bf16(a[mi], b,
                                                               acc[mi][t], 0, 0, 0);
      }
    }

    // -- late ds_write of the prefetched step
    if (hav) {
      unsigned short* dst = sh + (cur ^ 1) * 4096;
      *(uint4*)(dst + soff)        = pk8(p00, p01);
      *(uint4*)(dst + 2048 + soff) = pk8(p10, p11);
    }
    KBAR();            // lgkm-only: ds ops complete; global loads live on
    cur ^= 1;
  }
}

template<int NT0, int NT>
__device__ __forceinline__ void gemm1_epilogue(
    const float* __restrict__ b1, unsigned short* hidA, int lane,
    f32x4 (&acc)[4][4]) {
  const int ln = lane & 15, qd = lane >> 4;
  #pragma unroll
  for (int t = 0; t < NT; ++t) {
    const int n = (NT0 + t) * 16 + ln;
    if (n < HID) {
      const float bias = b1[n];
      const int kc2 = n >> 5, qd2 = (n >> 3) & 3, j2 = n & 7, c2 = kc2 & 7;
      #pragma unroll
      for (int mi = 0; mi < 4; ++mi)
        #pragma unroll
        for (int rr = 0; rr < 4; ++rr) {
          const int m = qd * 4 + rr;
          float h = fmaxf(acc[mi][t][rr] + bias, 0.f);
          __hip_bfloat16 hb = __float2bfloat16(h);
          hidA[mi * 3584 + (kc2 * 64 + qd2 * 16 + (m ^ c2)) * 8 + j2] =
              __builtin_bit_cast(unsigned short, hb);
        }
    }
  }
}

// ---------------------------------------------------------------------------
// fused10: fused6 structure with BK=64 (13 serialization points, was 25)
// and hidA overlaid on the aBuf LDS (28,672 B total; never both live —
// the post-loop full barrier separates all aBuf reads from hidA writes).
// ---------------------------------------------------------------------------
__global__ __launch_bounds__(256, 4) void fused10(
    const float* __restrict__ x, const unsigned short* __restrict__ w1e,
    const unsigned short* __restrict__ w2f, const float* __restrict__ b1,
    const float* __restrict__ b2, float* __restrict__ out) {
  __shared__ __align__(16) unsigned short sh[4 * 3584];   // 28,672 B
  const int tid  = threadIdx.x;
  const int wave = tid >> 6;
  const int lane = tid & 63;
  const int blk64 = blockIdx.x * MT2;

  f32x4 acc[4][4];
  #pragma unroll
  for (int mi = 0; mi < 4; ++mi)
    #pragma unroll
    for (int t = 0; t < 4; ++t) acc[mi][t] = (f32x4){0.f, 0.f, 0.f, 0.f};

  switch (wave) {
    case 0:  gemm1_compute<0, 4>(x, w1e, sh, lane, tid, blk64, acc); break;
    case 1:  gemm1_compute<4, 3>(x, w1e, sh, lane, tid, blk64, acc); break;
    case 2:  gemm1_compute<7, 3>(x, w1e, sh, lane, tid, blk64, acc); break;
    default: gemm1_compute<10, 3>(x, w1e, sh, lane, tid, blk64, acc); break;
  }
  __syncthreads();   // full drain: all aBuf reads done -> overlay hidA on sh

  // zero hid K-pad (k=200..223): 4 tiles x 16 rows x 12 dwords
  // (disjoint from epilogue's n<200 writes; both precede the next barrier)
  for (int i = tid; i < 768; i += 256) {
    int mi = i / 192, r = i - mi * 192, m = r / 12, d = r - m * 12;
    *(unsigned int*)fslot(sh + mi * 3584, m, 200 + 2 * d) = 0u;
  }
  switch (wave) {
    case 0:  gemm1_epilogue<0, 4>(b1, sh, lane, acc); break;
    case 1:  gemm1_epilogue<4, 3>(b1, sh, lane, acc); break;
    case 2:  gemm1_epilogue<7, 3>(b1, sh, lane, acc); break;
    default: gemm1_epilogue<10, 3>(b1, sh, lane, acc); break;
  }
  __syncthreads();   // hidA complete (incl. pads)

  // GEMM2: wave w handles m-tile w. 7 MFMA over K=224.
  const int ln = lane & 15, qd = lane >> 4;
  f32x4 acc2 = (f32x4){0.f, 0.f, 0.f, 0.f};
  #pragma unroll
  for (int kc = 0; kc < 7; ++kc) {
    bf16x8 a = *(const bf16x8*)&sh[wave * 3584 + (kc * 64 + (lane ^ (kc & 7))) * 8];
    bf16x8 b = *(const bf16x8*)(w2f + ((size_t)kc * 64 + lane) * 8);
    acc2 = __builtin_amdgcn_mfma_f32_16x16x32_bf16(a, b, acc2, 0, 0, 0);
  }
  if (ln < NCLS) {
    const float bb = b2[ln];
    #pragma unroll
    for (int rr = 0; rr < 4; ++rr) {
      out[((size_t)(blockIdx.x * 4 + wave) * 16 + qd * 4 + rr) * NCLS + ln] =
          acc2[rr] + bb;
    }
  }
}

extern "C" void kernel_launch(void* const* d_in, const int* in_sizes, int n_in,
                              void* d_out, int out_size, void* d_ws, size_t ws_size,
                              hipStream_t stream) {
  const float* x  = (const float*)d_in[0];
  const float* cw = (const float*)d_in[1];
  const float* w1 = (const float*)d_in[2];
  const float* b1 = (const float*)d_in[3];
  const float* w2 = (const float*)d_in[4];
  const float* b2 = (const float*)d_in[5];
  float* out = (float*)d_out;

  unsigned short* w1e = (unsigned short*)d_ws;                      // 346,112 B
  unsigned short* w2f = (unsigned short*)((char*)d_ws + 348160);    //   7,168 B

  hipLaunchKernelGGL(prep_weights, dim3(87), dim3(256), 0, stream,
                     w1, cw, w2, w1e, w2f);
  hipLaunchKernelGGL(fused10, dim3(GBLOCKS), dim3(256), 0, stream,
                     x, w1e, w2f, b1, b2, out);
}

// Round 13
// 318.111 us; speedup vs baseline: 1.0857x; 1.0236x over previous
//
#include <hip/hip_runtime.h>
#include <hip/hip_bf16.h>

// Problem constants
#define BATCH   65536
#define HW      28
#define OHW     26
#define HID     200
#define NCLS    10
#define MT2     64                  // images per gemm block (4 m-tiles)
#define GBLOCKS (BATCH / MT2)       // 1024
#define KC32    26                  // 32-wide B k-chunks: 784 -> 832 = 26*32
#define NSTEP   13                  // K-loop steps of BK=64

typedef __attribute__((ext_vector_type(8))) __bf16 bf16x8;
typedef __attribute__((ext_vector_type(4))) float  f32x4;

// DMA one 1 KB tile: 64 lanes x 16 B. LDS dest = wave-uniform base + lane*16
// (HW rule, m104); per-lane global source. The wave never touches the data.
#define STAGE16(g, l) __builtin_amdgcn_global_load_lds(                        \
    (const __attribute__((address_space(1))) void*)(g),                        \
    (__attribute__((address_space(3))) void*)(l), 16, 0, 0)

// Compiler-level memory fence: pins VMEM issue order between groups so the
// per-wave vmcnt ledgers below are valid (R12 lesson: without this the
// scheduler may reorder within a barrier window and the counts are wrong).
#define FENCE() asm volatile("" ::: "memory")

// Counted-vmcnt barriers (T3/T4: NEVER vmcnt(0) in the main loop).
// Ledger (pinned order, per window s):  B(s,h1)[NT] | B(s+1,h0)[NT] | stage(s+2)[4]
// main (s<=NSTEP-3): retire stage(s+1) -> all of window s is younger = 2NT+4.
template<int NT> __device__ __forceinline__ void kbar_main() {
  if constexpr (NT == 4)
    asm volatile("s_waitcnt vmcnt(12) lgkmcnt(0)\n\ts_barrier" ::: "memory");
  else
    asm volatile("s_waitcnt vmcnt(10) lgkmcnt(0)\n\ts_barrier" ::: "memory");
}
// tail (s=NSTEP-2, NSTEP-1): retire stage(12) -> window 11 = 2NT younger.
template<int NT> __device__ __forceinline__ void kbar_tail() {
  if constexpr (NT == 4)
    asm volatile("s_waitcnt vmcnt(8) lgkmcnt(0)\n\ts_barrier" ::: "memory");
  else
    asm volatile("s_waitcnt vmcnt(6) lgkmcnt(0)\n\ts_barrier" ::: "memory");
}
// prologue: retire stage(0) -> stage(1)[4]+B(0,h0)[NT] younger (fence-pinned).
template<int NT> __device__ __forceinline__ void kbar_pro() {
  if constexpr (NT == 4)
    asm volatile("s_waitcnt vmcnt(8) lgkmcnt(0)\n\ts_barrier" ::: "memory");
  else
    asm volatile("s_waitcnt vmcnt(7) lgkmcnt(0)\n\ts_barrier" ::: "memory");
}

__device__ __forceinline__ unsigned int pk2(float a, float b) {
  __hip_bfloat16 ha = __float2bfloat16(a), hb = __float2bfloat16(b);
  return (unsigned int)__builtin_bit_cast(unsigned short, ha)
       | ((unsigned int)__builtin_bit_cast(unsigned short, hb) << 16);
}

__device__ __forceinline__ uint4 pk8(float4 f0, float4 f1) {
  return make_uint4(pk2(f0.x, f0.y), pk2(f0.z, f0.w),
                    pk2(f1.x, f1.y), pk2(f1.z, f1.w));
}

// fslot: A-fragment layout with XOR swizzle, used ONLY for the hidA overlay.
__device__ __forceinline__ unsigned short* fslot(unsigned short* base, int m, int k) {
  const int kc = k >> 5;
  return base + ((kc * 64 + ((k >> 3) & 3) * 16 + (m ^ (kc & 7))) * 8) + (k & 7);
}

// ---------------------------------------------------------------------------
// prep_weights: w1e (conv folded into w1, B-fragment order, K pad 832 with
// k>=784 ZERO — the tail-garbage killer; N pad 208) + w2f. One dispatch.
// ---------------------------------------------------------------------------
__global__ __launch_bounds__(256) void prep_weights(
    const float* __restrict__ w1, const float* __restrict__ cwp,
    const float* __restrict__ w2, unsigned short* __restrict__ w1e,
    unsigned short* __restrict__ w2f) {
  if (blockIdx.x < 85) {
    int c = blockIdx.x * 256 + threadIdx.x;
    if (c >= KC32 * 13 * 64) return;
    int lane = c & 63, g = c >> 6;
    int kc = g / 13, nt = g - kc * 13;
    int ln = lane & 15, qd = lane >> 4;
    int n = nt * 16 + ln;
    float cw[9];
    #pragma unroll
    for (int t = 0; t < 9; ++t) cw[t] = cwp[t];
    float v[8];
    #pragma unroll
    for (int j = 0; j < 8; ++j) {
      int k = kc * 32 + qd * 8 + j;
      float s = 0.f;
      if (k < 784 && n < HID) {
        int ri = k / 28, ci = k - ri * 28;
        #pragma unroll
        for (int di = 0; di < 3; ++di) {
          int r = ri - di;
          if (r >= 0 && r < OHW) {
            #pragma unroll
            for (int dj = 0; dj < 3; ++dj) {
              int cc = ci - dj;
              if (cc >= 0 && cc < OHW)
                s += cw[di * 3 + dj] * w1[(r * OHW + cc) * HID + n];
            }
          }
        }
      }
      v[j] = s;
    }
    *(uint4*)(w1e + (size_t)c * 8) =
        make_uint4(pk2(v[0], v[1]), pk2(v[2], v[3]),
                   pk2(v[4], v[5]), pk2(v[6], v[7]));
  } else {
    int c = (blockIdx.x - 85) * 256 + threadIdx.x;
    if (c >= 7 * 64) return;
    int lane = c & 63, kc = c >> 6;
    int col = lane & 15;
    float v[8];
    #pragma unroll
    for (int j = 0; j < 8; ++j) {
      int k = kc * 32 + (lane >> 4) * 8 + j;
      v[j] = (col < NCLS && k < HID) ? w2[k * NCLS + col] : 0.f;
    }
    *(uint4*)(w2f + (size_t)c * 8) =
        make_uint4(pk2(v[0], v[1]), pk2(v[2], v[3]),
                   pk2(v[4], v[5]), pk2(v[6], v[7]));
  }
}

// ---------------------------------------------------------------------------
// GEMM1 compute: A staged by global_load_lds DMA in raw f32 (depth-2,
// triple-buffered 3x16KB); f32->bf16 cvt AFTER ds_read; B reg-prefetched.
// Unit map (16B units, 16/step): i = wave*4+j, U = i*64+lane:
//   p=lane&1, q6=(i&1)*32+(lane>>1), ln=q6&15, qd=q6>>4, mi=(i>>1)&3, h=i>>3
//   gsrc = x[blk64+mi*16+ln][s*64 + h*32 + qd*8 + p*4 ..+3]
//   lds float off = buf*4096 + h*2048 + mi*512 + (qd*16+ln)*8 + p*4
// Window issue order (FENCE-pinned): B(s,h1) | B(s+1,h0) | stage(s+2).
// Tail (stage of step 12): UNIFORM 4 ops/wave — real (offset 768) for the
// k<784 units (waves 0-1, j even), in-bounds dummy (offset 0) otherwise;
// dummy/stale units multiply w1e==0 columns.
// ---------------------------------------------------------------------------
template<int NT0, int NT>
__device__ __forceinline__ void gemm1_compute(
    const float* __restrict__ x, const unsigned short* __restrict__ w1e,
    unsigned short* sh, int lane, int wave, int blk64, f32x4 (&acc)[4][4]) {
  const float* gsrc[4];
  #pragma unroll
  for (int j = 0; j < 4; ++j) {
    const int i  = wave * 4 + j;
    const int p  = lane & 1;
    const int q6 = (i & 1) * 32 + (lane >> 1);
    const int ln_ = q6 & 15, qd_ = q6 >> 4;
    const int mi_ = (i >> 1) & 3, h_ = i >> 3;
    gsrc[j] = x + (size_t)(blk64 + mi_ * 16 + ln_) * 784 + h_ * 32 + qd_ * 8 + p * 4;
  }

  // prologue: stage(0)->buf0 | FENCE | stage(1)->buf1, B(0,h0) | kbar_pro
  #pragma unroll
  for (int j = 0; j < 4; ++j) STAGE16(gsrc[j], sh + (wave * 4 + j) * 512);
  FENCE();
  #pragma unroll
  for (int j = 0; j < 4; ++j) STAGE16(gsrc[j] + 64, sh + 8192 + (wave * 4 + j) * 512);
  bf16x8 bCur[NT];
  #pragma unroll
  for (int t = 0; t < NT; ++t)
    bCur[t] = *(const bf16x8*)(w1e + ((size_t)((NT0 + t) * 64 + lane)) * 8);
  kbar_pro<NT>();    // stage(0) forced; stage(1)+B(0) stay in flight

  #pragma unroll
  for (int s = 0; s < NSTEP; ++s) {
    const float* af = (const float*)(const void*)sh + (s % 3) * 4096;

    // (1) B(s,h1) — oldest group: its operand wait retires nothing critical
    bf16x8 bH1[NT];
    #pragma unroll
    for (int t = 0; t < NT; ++t)
      bH1[t] = *(const bf16x8*)(w1e +
                 ((size_t)((2 * s + 1) * 13 + NT0 + t) * 64 + lane) * 8);
    FENCE();
    // (2) B(s+1,h0) — BEFORE the stages, so its wait can't retire them
    bf16x8 bNx[NT];
    if (s + 1 < NSTEP) {
      #pragma unroll
      for (int t = 0; t < NT; ++t)
        bNx[t] = *(const bf16x8*)(w1e +
                   ((size_t)((2 * s + 2) * 13 + NT0 + t) * 64 + lane) * 8);
    }
    FENCE();
    // (3) stage(s+2) — youngest: survives all compiler operand waits
    if (s + 2 < NSTEP) {
      unsigned short* dst = sh + ((s + 2) % 3) * 8192;
      if (s + 2 == NSTEP - 1) {
        // uniform 4 ops/wave; real k=768..783 only for waves 0-1, j even
        #pragma unroll
        for (int j = 0; j < 4; ++j) {
          const int off = (wave < 2 && (j & 1) == 0) ? 768 : 0;
          STAGE16(gsrc[j] + off, dst + (wave * 4 + j) * 512);
        }
      } else {
        #pragma unroll
        for (int j = 0; j < 4; ++j)
          STAGE16(gsrc[j] + (s + 2) * 64, dst + (wave * 4 + j) * 512);
      }
    }
    FENCE();

    // (4) h=0: ds_read f32 + cvt + MFMA with bCur
    #pragma unroll
    for (int mi = 0; mi < 4; ++mi) {
      const float* ap = af + mi * 512 + lane * 8;
      float4 v0 = *(const float4*)ap;
      float4 v1 = *(const float4*)(ap + 4);
      bf16x8 a = __builtin_bit_cast(bf16x8, pk8(v0, v1));
      #pragma unroll
      for (int t = 0; t < NT; ++t)
        acc[mi][t] = __builtin_amdgcn_mfma_f32_16x16x32_bf16(a, bCur[t],
                                                             acc[mi][t], 0, 0, 0);
    }
    // (5) h=1: MFMA with bH1
    #pragma unroll
    for (int mi = 0; mi < 4; ++mi) {
      const float* ap = af + 2048 + mi * 512 + lane * 8;
      float4 v0 = *(const float4*)ap;
      float4 v1 = *(const float4*)(ap + 4);
      bf16x8 a = __builtin_bit_cast(bf16x8, pk8(v0, v1));
      #pragma unroll
      for (int t = 0; t < NT; ++t)
        acc[mi][t] = __builtin_amdgcn_mfma_f32_16x16x32_bf16(a, bH1[t],
                                                             acc[mi][t], 0, 0, 0);
    }
    if (s + 1 < NSTEP) {
      #pragma unroll
      for (int t = 0; t < NT; ++t) bCur[t] = bNx[t];
    }
    if (s < NSTEP - 2) kbar_main<NT>(); else kbar_tail<NT>();
  }
}

template<int NT0, int NT>
__device__ __forceinline__ void gemm1_epilogue(
    const float* __restrict__ b1, unsigned short* hidA, int lane,
    f32x4 (&acc)[4][4]) {
  const int ln = lane & 15, qd = lane >> 4;
  #pragma unroll
  for (int t = 0; t < NT; ++t) {
    const int n = (NT0 + t) * 16 + ln;
    if (n < HID) {
      const float bias = b1[n];
      const int kc2 = n >> 5, qd2 = (n >> 3) & 3, j2 = n & 7, c2 = kc2 & 7;
      #pragma unroll
      for (int mi = 0; mi < 4; ++mi)
        #pragma unroll
        for (int rr = 0; rr < 4; ++rr) {
          const int m = qd * 4 + rr;
          float h = fmaxf(acc[mi][t][rr] + bias, 0.f);
          __hip_bfloat16 hb = __float2bfloat16(h);
          hidA[mi * 3584 + (kc2 * 64 + qd2 * 16 + (m ^ c2)) * 8 + j2] =
              __builtin_bit_cast(unsigned short, hb);
        }
    }
  }
}

// ---------------------------------------------------------------------------
// fused12: fused11 with the three vmcnt-ledger races fixed (fences, robust
// counts, uniform tail). LDS = 3x16KB; hidA overlays after the K-loop.
// ---------------------------------------------------------------------------
__global__ __launch_bounds__(256, 3) void fused12(
    const float* __restrict__ x, const unsigned short* __restrict__ w1e,
    const unsigned short* __restrict__ w2f, const float* __restrict__ b1,
    const float* __restrict__ b2, float* __restrict__ out) {
  __shared__ __align__(16) unsigned short sh[3 * 8192];   // 49,152 B
  const int tid  = threadIdx.x;
  const int wave = tid >> 6;
  const int lane = tid & 63;
  const int blk64 = blockIdx.x * MT2;

  f32x4 acc[4][4];
  #pragma unroll
  for (int mi = 0; mi < 4; ++mi)
    #pragma unroll
    for (int t = 0; t < 4; ++t) acc[mi][t] = (f32x4){0.f, 0.f, 0.f, 0.f};

  switch (wave) {
    case 0:  gemm1_compute<0, 4>(x, w1e, sh, lane, wave, blk64, acc); break;
    case 1:  gemm1_compute<4, 3>(x, w1e, sh, lane, wave, blk64, acc); break;
    case 2:  gemm1_compute<7, 3>(x, w1e, sh, lane, wave, blk64, acc); break;
    default: gemm1_compute<10, 3>(x, w1e, sh, lane, wave, blk64, acc); break;
  }
  __syncthreads();   // full drain once: all DMAs + reads done -> overlay hidA

  // zero hid K-pad (k=200..223): 4 tiles x 16 rows x 12 dwords
  for (int i = tid; i < 768; i += 256) {
    int mi = i / 192, r = i - mi * 192, m = r / 12, d = r - m * 12;
    *(unsigned int*)fslot(sh + mi * 3584, m, 200 + 2 * d) = 0u;
  }
  switch (wave) {
    case 0:  gemm1_epilogue<0, 4>(b1, sh, lane, acc); break;
    case 1:  gemm1_epilogue<4, 3>(b1, sh, lane, acc); break;
    case 2:  gemm1_epilogue<7, 3>(b1, sh, lane, acc); break;
    default: gemm1_epilogue<10, 3>(b1, sh, lane, acc); break;
  }
  __syncthreads();   // hidA complete (incl. pads)

  // GEMM2: wave w handles m-tile w. 7 MFMA over K=224.
  const int ln = lane & 15, qd = lane >> 4;
  f32x4 acc2 = (f32x4){0.f, 0.f, 0.f, 0.f};
  #pragma unroll
  for (int kc = 0; kc < 7; ++kc) {
    bf16x8 a = *(const bf16x8*)&sh[wave * 3584 + (kc * 64 + (lane ^ (kc & 7))) * 8];
    bf16x8 b = *(const bf16x8*)(w2f + ((size_t)kc * 64 + lane) * 8);
    acc2 = __builtin_amdgcn_mfma_f32_16x16x32_bf16(a, b, acc2, 0, 0, 0);
  }
  if (ln < NCLS) {
    const float bb = b2[ln];
    #pragma unroll
    for (int rr = 0; rr < 4; ++rr) {
      out[((size_t)(blockIdx.x * 4 + wave) * 16 + qd * 4 + rr) * NCLS + ln] =
          acc2[rr] + bb;
    }
  }
}

extern "C" void kernel_launch(void* const* d_in, const int* in_sizes, int n_in,
                              void* d_out, int out_size, void* d_ws, size_t ws_size,
                              hipStream_t stream) {
  const float* x  = (const float*)d_in[0];
  const float* cw = (const float*)d_in[1];
  const float* w1 = (const float*)d_in[2];
  const float* b1 = (const float*)d_in[3];
  const float* w2 = (const float*)d_in[4];
  const float* b2 = (const float*)d_in[5];
  float* out = (float*)d_out;

  unsigned short* w1e = (unsigned short*)d_ws;                      // 346,112 B
  unsigned short* w2f = (unsigned short*)((char*)d_ws + 348160);    //   7,168 B

  hipLaunchKernelGGL(prep_weights, dim3(87), dim3(256), 0, stream,
                     w1, cw, w2, w1e, w2f);
  hipLaunchKernelGGL(fused12, dim3(GBLOCKS), dim3(256), 0, stream,
                     x, w1e, w2f, b1, b2, out);
}